// Round 10
// baseline (204.079 us; speedup 1.0000x reference)
//
#include <hip/hip_runtime.h>

#define E_EDGES 20000
#define D_DIM   128
#define NBA     136       // W2/b2 repack blocks: 128 W2 + 1 bias + 7 zero (prefetch pad)
#define NBC     184       // hw fp32->fp16 cast blocks (grid-stride)
#define SLAB_B  21504     // per-block hidden slab: 80 edges x 264B (132 h fp16 + pad)

typedef _Float16 f16x8 __attribute__((ext_vector_type(8)));
typedef _Float16 f16x4 __attribute__((ext_vector_type(4)));
typedef _Float16 f16x2 __attribute__((ext_vector_type(2)));
typedef float    floatx4 __attribute__((ext_vector_type(4)));

union F8 { f16x8 v; f16x2 h2[4]; unsigned int u[4]; };
union F4 { f16x4 v; f16x2 h2[2]; unsigned int u[2]; };

__device__ __forceinline__ unsigned short f32_to_f16(float f) {
    _Float16 h = (_Float16)f;
    return __builtin_bit_cast(unsigned short, h);
}

// ---------------------------------------------------------------------------
// prep_all: (A) repack W2/b2 h-slices into fragment-major fp16 bpf (one
// h-slice per block, ~4 us); (B) grid-stride cast h_w fp32 -> fp16 hwb.
// The fp16 hwb matters twice: it halves the hws load traffic AND (r9 vs r5
// lesson) it removes the fp32->f16 convert temps from edge_main's prologue —
// that peak-pressure difference is what made r5 spill at the 128-reg cap
// while r9's body allocates 112 total.
// ---------------------------------------------------------------------------
__global__ __launch_bounds__(256) void prep_all(
    const float* __restrict__ W2, const float* __restrict__ b2,
    const float* __restrict__ hw,
    uint4* __restrict__ bpf, unsigned short* __restrict__ hwb)
{
    __shared__ __align__(16) unsigned short tile[17408];   // [col][136]
    const int bx = blockIdx.x;
    const int t  = threadIdx.x;

    if (bx < NBA) {
        const int h = bx;
        if (h < 129) {
            const float* src = (h < 128) ? (W2 + (size_t)h * (D_DIM * D_DIM)) : b2;
            #pragma unroll
            for (int r = 0; r < 16; ++r) {
                const float4 v = ((const float4*)src)[r * 256 + t];
                int c   = (r * 256 + t) * 4;
                int col = c >> 7;
                int k   = c & 127;
                unsigned int u0 = f32_to_f16(v.x) | ((unsigned int)f32_to_f16(v.y) << 16);
                unsigned int u1 = f32_to_f16(v.z) | ((unsigned int)f32_to_f16(v.w) << 16);
                *(uint2*)&tile[col * 136 + k] = make_uint2(u0, u1);
            }
            __syncthreads();
            #pragma unroll
            for (int r2 = 0; r2 < 8; ++r2) {
                int cidx = r2 * 256 + t;
                int ll = cidx & 63;
                int nt = (cidx >> 6) & 1;
                int jq = (cidx >> 7) & 3;
                int ch = (cidx >> 9) & 3;
                int col = 32 * ch + 16 * nt + (ll & 15);
                int k0  = 32 * jq + 8 * (ll >> 4);
                bpf[(size_t)h * 2048 + cidx] = *(const uint4*)&tile[col * 136 + k0];
            }
        } else {
            // zero-fill pad slices so prefetch reads never feed garbage into MFMA
            #pragma unroll
            for (int r2 = 0; r2 < 8; ++r2)
                bpf[(size_t)h * 2048 + r2 * 256 + t] = make_uint4(0, 0, 0, 0);
        }
    } else {
        int i0 = (bx - NBA) * 256 + t;
        for (int i = i0; i < (E_EDGES * D_DIM) / 4; i += NBC * 256) {
            const float4 v = ((const float4*)hw)[i];
            union { unsigned short u16[4]; uint2 u2; } o;
            o.u16[0] = f32_to_f16(v.x);
            o.u16[1] = f32_to_f16(v.y);
            o.u16[2] = f32_to_f16(v.z);
            o.u16[3] = f32_to_f16(v.w);
            ((uint2*)hwb)[i] = o.u2;
        }
    }
}

// ---------------------------------------------------------------------------
// Main (Z-GEMM v12: all-resident): 1000 blocks x 256 threads, 4 blocks/CU.
// r6/r8/r9 established: per-block overhead ~tens of us makes finer work
// partitioning a loss; the r6 wall (82.7) was cohort quantization (1000
// blocks into 768 slots at 3/CU = 2 x 41.4 us). Fix: make the body fit
// 4 blocks/CU so ALL 1000 blocks are resident at once (1024 slots) — no
// cohorts, no atomics, plain stores. r9's body measures 72 arch + 40 acc
// = 112 total regs (fp16-hwb hws is what keeps peak pressure low; fp32-hws
// r5 spilled at this cap) -> fits the 128 cap of __launch_bounds__(256,4).
// Block = (eg 0..249) x (ch 0..3), full h 0..131. bx&7 -> XCD round-robin
// pins each XCD to a fixed 1.1 MB bpf slice (L2-resident).
// Body: depth-4 B register prefetch B[4][2]; hid ds_read ping-pong; fused
// MLP slab (one mfma 16x16x16f16 per (m,nn)); hws from fp16 hwb.
// MFMA floor at 100% util: 5.28M mfma x 19.4 cyc / 1024 SIMD = 41.7 us.
// Tripwire: FETCH or WRITE inflation (>100 MB) = spill -> revert (256,3).
// ---------------------------------------------------------------------------
__global__ __launch_bounds__(256, 4)
void edge_main(const uint4* __restrict__ bpf, const uint4* __restrict__ hwb,
               const float* __restrict__ ef, const float* __restrict__ W1,
               const float* __restrict__ b1, float* __restrict__ out)
{
    __shared__ __align__(16) char slab[SLAB_B];
    const int bx  = blockIdx.x;
    const int ch  = bx & 3;                   // col-quarter
    const int eg  = bx >> 2;                  // 0..249
    const int tid = threadIdx.x;
    const int jq  = tid >> 6;                 // j-quarter, 0..3
    const int l   = tid & 63;
    const int l4  = l >> 4;
    const int lm  = l & 15;
    const int e0  = eg * 80;                  // 250*80 = 20000 exact, no masks
    const int cbase = ch * 512 + jq * 128 + l;
    const f16x8* bpf8 = (const f16x8*)bpf;

    // ---- resident h_w A-source (fp16, prep-cast): issue at kernel entry ----
    F8 hws[5];
    #pragma unroll
    for (int m = 0; m < 5; ++m)
        hws[m].v = ((const F8*)hwb)[(e0 + 16 * m + lm) * 16 + 4 * jq + l4].v;

    // ---- depth-4 B register prefetch prologue ----
    f16x8 B[4][2];
    auto loadB = [&](int h, f16x8 (&Bq)[2]) {
        const f16x8* p = bpf8 + (size_t)h * 2048 + cbase;
        Bq[0] = p[0];
        Bq[1] = p[64];                        // 2 x 1KB contiguous per wave
    };
    loadB(0, B[0]);
    loadB(1, B[1]);
    loadB(2, B[2]);
    loadB(3, B[3]);

    // ---- fused edge-MLP: hidden = relu(ef @ W1 + b1) -> slab fp16 [80][132] ----
    // A: ef rows (K=16 = edge_dim, one MFMA). A-frag: row=l&15, k=4*l4+i.
    // B: W1 cols. Wave jq covers h-cols [32jq, 32jq+32) as two 16-col tiles.
    {
        F4 A[5];
        #pragma unroll
        for (int m = 0; m < 5; ++m) {
            const float4 q4 = *(const float4*)(ef + (size_t)(e0 + 16 * m + lm) * 16 + 4 * l4);
            A[m].h2[0] = (f16x2){(_Float16)q4.x, (_Float16)q4.y};
            A[m].h2[1] = (f16x2){(_Float16)q4.z, (_Float16)q4.w};
        }
        F4 Bw[2];
        float bv[2];
        #pragma unroll
        for (int nn = 0; nn < 2; ++nn) {
            const int col = jq * 32 + nn * 16 + lm;
            float w0 = W1[(4 * l4 + 0) * 128 + col];
            float w1 = W1[(4 * l4 + 1) * 128 + col];
            float w2 = W1[(4 * l4 + 2) * 128 + col];
            float w3 = W1[(4 * l4 + 3) * 128 + col];
            Bw[nn].h2[0] = (f16x2){(_Float16)w0, (_Float16)w1};
            Bw[nn].h2[1] = (f16x2){(_Float16)w2, (_Float16)w3};
            bv[nn] = b1[col];
        }
        #pragma unroll
        for (int m = 0; m < 5; ++m) {
            floatx4 H0 = (floatx4){bv[0], bv[0], bv[0], bv[0]};
            floatx4 H1 = (floatx4){bv[1], bv[1], bv[1], bv[1]};
            H0 = __builtin_amdgcn_mfma_f32_16x16x16f16(A[m].v, Bw[0].v, H0, 0, 0, 0);
            H1 = __builtin_amdgcn_mfma_f32_16x16x16f16(A[m].v, Bw[1].v, H1, 0, 0, 0);
            #pragma unroll
            for (int r = 0; r < 4; ++r) {
                const int e = 16 * m + 4 * l4 + r;          // D: row=4*l4+r, col=lm
                *(unsigned short*)(slab + e * 264 + (jq * 32 + lm) * 2) =
                    f32_to_f16(fmaxf(H0[r], 0.f));
                *(unsigned short*)(slab + e * 264 + (jq * 32 + 16 + lm) * 2) =
                    f32_to_f16(fmaxf(H1[r], 0.f));
            }
        }
        if (tid < 80) {
            *(unsigned int*)(slab + tid * 264 + 256) = 0x00003C00u; // h=128: 1.0, h=129: 0
            *(unsigned int*)(slab + tid * 264 + 260) = 0u;          // h=130,131: 0
        }
    }

    floatx4 C[5][2];
    #pragma unroll
    for (int m = 0; m < 5; ++m)
        #pragma unroll
        for (int nt = 0; nt < 2; ++nt)
            C[m][nt] = (floatx4){0.f, 0.f, 0.f, 0.f};

    __syncthreads();    // slab (hidden) complete; only barrier before epilogue

    auto doH = [&](int h, const uint2 (&hid)[5]) {
        const int hh4 = h & 3;
        #pragma unroll
        for (int m = 0; m < 5; ++m) {
            unsigned int s   = (hh4 < 2) ? hid[m].x : hid[m].y;
            unsigned int sel = (hh4 & 1) ? 0x03020302u : 0x01000100u;
            f16x2 d = __builtin_bit_cast(f16x2, __builtin_amdgcn_perm(0u, s, sel));
            F8 a;
            #pragma unroll
            for (int i = 0; i < 4; ++i) a.h2[i] = hws[m].h2[i] * d;
            C[m][0] = __builtin_amdgcn_mfma_f32_16x16x32_f16(a.v, B[hh4][0], C[m][0], 0, 0, 0);
            C[m][1] = __builtin_amdgcn_mfma_f32_16x16x32_f16(a.v, B[hh4][1], C[m][1], 0, 0, 0);
        }
        loadB(h + 4, B[hh4]);                 // refill (max h+4 = 135 < 136)
    };
    auto readHid = [&](int q, uint2 (&hid)[5]) {
        #pragma unroll
        for (int m = 0; m < 5; ++m)           // broadcast ds_read_b64 (l4 ignored)
            hid[m] = *(const uint2*)(slab + (16 * m + lm) * 264 + q * 8);
    };

    uint2 hid0[5], hid1[5];
    readHid(0, hid0);
    #pragma unroll 1
    for (int q = 0; q < 32; q += 2) {         // h-quads q, q+1 (h = 4q .. 4q+7)
        readHid(q + 1, hid1);                 // prefetch next quad's hid
        doH(4 * q + 0, hid0);
        doH(4 * q + 1, hid0);
        doH(4 * q + 2, hid0);
        doH(4 * q + 3, hid0);
        readHid(q + 2, hid0);                 // q+2 <= 32: row bytes 256..263 exist
        doH(4 * q + 4, hid1);
        doH(4 * q + 5, hid1);
        doH(4 * q + 6, hid1);
        doH(4 * q + 7, hid1);
    }
    // q = 32 tail: h = 128..131 (bias row + zero pads), hid0 read in last iter
    doH(128, hid0);
    doH(129, hid0);
    doH(130, hid0);
    doH(131, hid0);

    // epilogue: reduce the 4 jq partials in-block via LDS (reuse slab: 10240B),
    // then plain coalesced stores. C/D layout: col = lane&15, row = 4*(lane>>4)+r.
    float* red = (float*)slab;
    #pragma unroll 1
    for (int src = 1; src < 4; ++src) {
        __syncthreads();
        if (jq == src) {
            #pragma unroll
            for (int m = 0; m < 5; ++m)
                #pragma unroll
                for (int nt = 0; nt < 2; ++nt)
                    #pragma unroll
                    for (int r = 0; r < 4; ++r)
                        red[((m * 2 + nt) * 4 + r) * 64 + l] = C[m][nt][r];
        }
        __syncthreads();
        if (jq == 0) {
            #pragma unroll
            for (int m = 0; m < 5; ++m)
                #pragma unroll
                for (int nt = 0; nt < 2; ++nt)
                    #pragma unroll
                    for (int r = 0; r < 4; ++r)
                        C[m][nt][r] += red[((m * 2 + nt) * 4 + r) * 64 + l];
        }
    }
    if (jq == 0) {
        #pragma unroll
        for (int m = 0; m < 5; ++m)
            #pragma unroll
            for (int nt = 0; nt < 2; ++nt)
                #pragma unroll
                for (int r = 0; r < 4; ++r)
                    out[(size_t)(e0 + 16 * m + 4 * l4 + r) * D_DIM
                        + 32 * ch + 16 * nt + lm] = C[m][nt][r];
    }
}

// ---------------------------------------------------------------------------
extern "C" void kernel_launch(void* const* d_in, const int* in_sizes, int n_in,
                              void* d_out, int out_size, void* d_ws, size_t ws_size,
                              hipStream_t stream) {
    // inputs: h_v, h_w, edge_features, W1, b1, W2, b2 (fp32; h_v unused)
    const float* h_w = (const float*)d_in[1];
    const float* ef  = (const float*)d_in[2];
    const float* W1  = (const float*)d_in[3];
    const float* b1  = (const float*)d_in[4];
    const float* W2  = (const float*)d_in[5];
    const float* b2  = (const float*)d_in[6];
    float* out = (float*)d_out;

    char* ws = (char*)d_ws;
    uint4*          bpf = (uint4*)ws;                         // 4,456,448 B
    unsigned short* hwb = (unsigned short*)(ws + 4456448);    // 5,120,000 B
    // total ws use: 9,576,448 B

    hipLaunchKernelGGL(prep_all, dim3(NBA + NBC), dim3(256), 0, stream,
                       W2, b2, h_w, bpf, hwb);
    hipLaunchKernelGGL(edge_main, dim3(1000), dim3(256), 0, stream,
                       bpf, (const uint4*)hwb, ef, W1, b1, out);
}

// Round 11
// 164.526 us; speedup vs baseline: 1.2404x; 1.2404x over previous
//
#include <hip/hip_runtime.h>

#define E_EDGES 20000
#define D_DIM   128
#define NBA     136       // W2/b2 repack blocks: 128 W2 + 1 bias + 7 zero (prefetch pad)
#define NBC     184       // hw fp32->fp16 cast blocks (grid-stride)
#define SLAB_B  21504     // per-block hidden slab: 80 edges x 264B (132 h fp16 + pad)

typedef _Float16 f16x8 __attribute__((ext_vector_type(8)));
typedef _Float16 f16x4 __attribute__((ext_vector_type(4)));
typedef _Float16 f16x2 __attribute__((ext_vector_type(2)));
typedef float    floatx4 __attribute__((ext_vector_type(4)));

union F8 { f16x8 v; f16x2 h2[4]; unsigned int u[4]; };
union F4 { f16x4 v; f16x2 h2[2]; unsigned int u[2]; };

__device__ __forceinline__ unsigned short f32_to_f16(float f) {
    _Float16 h = (_Float16)f;
    return __builtin_bit_cast(unsigned short, h);
}

// ---------------------------------------------------------------------------
// prep_all: (A) repack W2/b2 h-slices into fragment-major fp16 bpf (one
// h-slice per block, ~4 us); (B) grid-stride cast h_w fp32 -> fp16 hwb
// (fp16 hwb halves hws traffic AND keeps edge_main's prologue peak register
// pressure low — fp32-hws variants spilled under launch_bounds caps).
// ---------------------------------------------------------------------------
__global__ __launch_bounds__(256) void prep_all(
    const float* __restrict__ W2, const float* __restrict__ b2,
    const float* __restrict__ hw,
    uint4* __restrict__ bpf, unsigned short* __restrict__ hwb)
{
    __shared__ __align__(16) unsigned short tile[17408];   // [col][136]
    const int bx = blockIdx.x;
    const int t  = threadIdx.x;

    if (bx < NBA) {
        const int h = bx;
        if (h < 129) {
            const float* src = (h < 128) ? (W2 + (size_t)h * (D_DIM * D_DIM)) : b2;
            #pragma unroll
            for (int r = 0; r < 16; ++r) {
                const float4 v = ((const float4*)src)[r * 256 + t];
                int c   = (r * 256 + t) * 4;
                int col = c >> 7;
                int k   = c & 127;
                unsigned int u0 = f32_to_f16(v.x) | ((unsigned int)f32_to_f16(v.y) << 16);
                unsigned int u1 = f32_to_f16(v.z) | ((unsigned int)f32_to_f16(v.w) << 16);
                *(uint2*)&tile[col * 136 + k] = make_uint2(u0, u1);
            }
            __syncthreads();
            #pragma unroll
            for (int r2 = 0; r2 < 8; ++r2) {
                int cidx = r2 * 256 + t;
                int ll = cidx & 63;
                int nt = (cidx >> 6) & 1;
                int jq = (cidx >> 7) & 3;
                int ch = (cidx >> 9) & 3;
                int col = 32 * ch + 16 * nt + (ll & 15);
                int k0  = 32 * jq + 8 * (ll >> 4);
                bpf[(size_t)h * 2048 + cidx] = *(const uint4*)&tile[col * 136 + k0];
            }
        } else {
            // zero-fill pad slices so prefetch reads never feed garbage into MFMA
            #pragma unroll
            for (int r2 = 0; r2 < 8; ++r2)
                bpf[(size_t)h * 2048 + r2 * 256 + t] = make_uint4(0, 0, 0, 0);
        }
    } else {
        int i0 = (bx - NBA) * 256 + t;
        for (int i = i0; i < (E_EDGES * D_DIM) / 4; i += NBC * 256) {
            const float4 v = ((const float4*)hw)[i];
            union { unsigned short u16[4]; uint2 u2; } o;
            o.u16[0] = f32_to_f16(v.x);
            o.u16[1] = f32_to_f16(v.y);
            o.u16[2] = f32_to_f16(v.z);
            o.u16[3] = f32_to_f16(v.w);
            ((uint2*)hwb)[i] = o.u2;
        }
    }
}

// ---------------------------------------------------------------------------
// Main (Z-GEMM v13: depth-2, all-resident): 1000 blocks x 256, 4 blocks/CU.
// The register ledger across r0-r10: depth-4 B[4][2] bodies are >128 total
// regs (unified VGPR+AGPR) and SPILL under bounds(256,4) (r5: 337 MB, r10:
// 253 MB scratch writes); r0's depth-2 body measured 92 total at 4/CU clean.
// r6's cohort-1 proved 3-resident runs this body at 77% MfmaUtil — its 82.7
// wall was purely the 768+232 cohort split. Single change vs r9/r10: B
// prefetch depth 4 -> 2 (r0's exact refill: consume B[h&1], reload h+2),
// saving 32 regs -> ~116 high-water, fits the 128 cap -> grid 1000 fully
// resident in 1024 slots: ONE cohort, plain stores, no atomics.
// Kept from r3/r9: hid ds_read ping-pong, fused MLP slab prologue, fp16 hwb
// hws issued at entry, ch = bx&3 XCD-pinned bpf slice (1.1 MB/XCD L2).
// MFMA floor at 100% util: 5.28M mfma x 19.4 cyc / 1024 SIMD = 41.7 us.
// Tripwire: WRITE_SIZE must be 10 MB. Inflated -> spill -> revert (256,3).
// ---------------------------------------------------------------------------
__global__ __launch_bounds__(256, 4)
void edge_main(const uint4* __restrict__ bpf, const uint4* __restrict__ hwb,
               const float* __restrict__ ef, const float* __restrict__ W1,
               const float* __restrict__ b1, float* __restrict__ out)
{
    __shared__ __align__(16) char slab[SLAB_B];
    const int bx  = blockIdx.x;
    const int ch  = bx & 3;                   // col-quarter, constant per XCD
    const int eg  = bx >> 2;                  // 0..249
    const int tid = threadIdx.x;
    const int jq  = tid >> 6;                 // j-quarter, 0..3
    const int l   = tid & 63;
    const int l4  = l >> 4;
    const int lm  = l & 15;
    const int e0  = eg * 80;                  // 250*80 = 20000 exact, no masks
    const int cbase = ch * 512 + jq * 128 + l;
    const f16x8* bpf8 = (const f16x8*)bpf;

    // ---- resident h_w A-source (fp16, prep-cast): issue at kernel entry ----
    F8 hws[5];
    #pragma unroll
    for (int m = 0; m < 5; ++m)
        hws[m].v = ((const F8*)hwb)[(e0 + 16 * m + lm) * 16 + 4 * jq + l4].v;

    // ---- depth-2 B register prefetch prologue (r0-proven register shape) ----
    f16x8 B[2][2];
    auto loadB = [&](int h, f16x8 (&Bq)[2]) {
        const f16x8* p = bpf8 + (size_t)h * 2048 + cbase;
        Bq[0] = p[0];
        Bq[1] = p[64];                        // 2 x 1KB contiguous per wave
    };
    loadB(0, B[0]);
    loadB(1, B[1]);

    // ---- fused edge-MLP: hidden = relu(ef @ W1 + b1) -> slab fp16 [80][132] ----
    // A: ef rows (K=16 = edge_dim, one MFMA). A-frag: row=l&15, k=4*l4+i.
    // B: W1 cols. Wave jq covers h-cols [32jq, 32jq+32) as two 16-col tiles.
    {
        F4 A[5];
        #pragma unroll
        for (int m = 0; m < 5; ++m) {
            const float4 q4 = *(const float4*)(ef + (size_t)(e0 + 16 * m + lm) * 16 + 4 * l4);
            A[m].h2[0] = (f16x2){(_Float16)q4.x, (_Float16)q4.y};
            A[m].h2[1] = (f16x2){(_Float16)q4.z, (_Float16)q4.w};
        }
        F4 Bw[2];
        float bv[2];
        #pragma unroll
        for (int nn = 0; nn < 2; ++nn) {
            const int col = jq * 32 + nn * 16 + lm;
            float w0 = W1[(4 * l4 + 0) * 128 + col];
            float w1 = W1[(4 * l4 + 1) * 128 + col];
            float w2 = W1[(4 * l4 + 2) * 128 + col];
            float w3 = W1[(4 * l4 + 3) * 128 + col];
            Bw[nn].h2[0] = (f16x2){(_Float16)w0, (_Float16)w1};
            Bw[nn].h2[1] = (f16x2){(_Float16)w2, (_Float16)w3};
            bv[nn] = b1[col];
        }
        #pragma unroll
        for (int m = 0; m < 5; ++m) {
            floatx4 H0 = (floatx4){bv[0], bv[0], bv[0], bv[0]};
            floatx4 H1 = (floatx4){bv[1], bv[1], bv[1], bv[1]};
            H0 = __builtin_amdgcn_mfma_f32_16x16x16f16(A[m].v, Bw[0].v, H0, 0, 0, 0);
            H1 = __builtin_amdgcn_mfma_f32_16x16x16f16(A[m].v, Bw[1].v, H1, 0, 0, 0);
            #pragma unroll
            for (int r = 0; r < 4; ++r) {
                const int e = 16 * m + 4 * l4 + r;          // D: row=4*l4+r, col=lm
                *(unsigned short*)(slab + e * 264 + (jq * 32 + lm) * 2) =
                    f32_to_f16(fmaxf(H0[r], 0.f));
                *(unsigned short*)(slab + e * 264 + (jq * 32 + 16 + lm) * 2) =
                    f32_to_f16(fmaxf(H1[r], 0.f));
            }
        }
        if (tid < 80) {
            *(unsigned int*)(slab + tid * 264 + 256) = 0x00003C00u; // h=128: 1.0, h=129: 0
            *(unsigned int*)(slab + tid * 264 + 260) = 0u;          // h=130,131: 0
        }
    }

    floatx4 C[5][2];
    #pragma unroll
    for (int m = 0; m < 5; ++m)
        #pragma unroll
        for (int nt = 0; nt < 2; ++nt)
            C[m][nt] = (floatx4){0.f, 0.f, 0.f, 0.f};

    __syncthreads();    // slab (hidden) complete; only barrier before epilogue

    auto doH = [&](int h, const uint2 (&hid)[5]) {
        const int hh4 = h & 3, p = h & 1;
        #pragma unroll
        for (int m = 0; m < 5; ++m) {
            unsigned int s   = (hh4 < 2) ? hid[m].x : hid[m].y;
            unsigned int sel = (hh4 & 1) ? 0x03020302u : 0x01000100u;
            f16x2 d = __builtin_bit_cast(f16x2, __builtin_amdgcn_perm(0u, s, sel));
            F8 a;
            #pragma unroll
            for (int i = 0; i < 4; ++i) a.h2[i] = hws[m].h2[i] * d;
            C[m][0] = __builtin_amdgcn_mfma_f32_16x16x32_f16(a.v, B[p][0], C[m][0], 0, 0, 0);
            C[m][1] = __builtin_amdgcn_mfma_f32_16x16x32_f16(a.v, B[p][1], C[m][1], 0, 0, 0);
        }
        loadB(h + 2, B[p]);                   // refill just-consumed buffer (h+2 <= 133 < 136)
    };
    auto readHid = [&](int q, uint2 (&hid)[5]) {
        #pragma unroll
        for (int m = 0; m < 5; ++m)           // broadcast ds_read_b64 (l4 ignored)
            hid[m] = *(const uint2*)(slab + (16 * m + lm) * 264 + q * 8);
    };

    uint2 hid0[5], hid1[5];
    readHid(0, hid0);
    #pragma unroll 1
    for (int q = 0; q < 32; q += 2) {         // h-quads q, q+1 (h = 4q .. 4q+7)
        readHid(q + 1, hid1);                 // prefetch next quad's hid
        doH(4 * q + 0, hid0);
        doH(4 * q + 1, hid0);
        doH(4 * q + 2, hid0);
        doH(4 * q + 3, hid0);
        readHid(q + 2, hid0);                 // q+2 <= 32: row bytes 256..263 exist
        doH(4 * q + 4, hid1);
        doH(4 * q + 5, hid1);
        doH(4 * q + 6, hid1);
        doH(4 * q + 7, hid1);
    }
    // q = 32 tail: h = 128..131 (bias row + zero pads), hid0 read in last iter
    doH(128, hid0);
    doH(129, hid0);
    doH(130, hid0);
    doH(131, hid0);

    // epilogue: reduce the 4 jq partials in-block via LDS (reuse slab: 10240B),
    // then plain coalesced stores. C/D layout: col = lane&15, row = 4*(lane>>4)+r.
    float* red = (float*)slab;
    #pragma unroll 1
    for (int src = 1; src < 4; ++src) {
        __syncthreads();
        if (jq == src) {
            #pragma unroll
            for (int m = 0; m < 5; ++m)
                #pragma unroll
                for (int nt = 0; nt < 2; ++nt)
                    #pragma unroll
                    for (int r = 0; r < 4; ++r)
                        red[((m * 2 + nt) * 4 + r) * 64 + l] = C[m][nt][r];
        }
        __syncthreads();
        if (jq == 0) {
            #pragma unroll
            for (int m = 0; m < 5; ++m)
                #pragma unroll
                for (int nt = 0; nt < 2; ++nt)
                    #pragma unroll
                    for (int r = 0; r < 4; ++r)
                        C[m][nt][r] += red[((m * 2 + nt) * 4 + r) * 64 + l];
        }
    }
    if (jq == 0) {
        #pragma unroll
        for (int m = 0; m < 5; ++m)
            #pragma unroll
            for (int nt = 0; nt < 2; ++nt)
                #pragma unroll
                for (int r = 0; r < 4; ++r)
                    out[(size_t)(e0 + 16 * m + 4 * l4 + r) * D_DIM
                        + 32 * ch + 16 * nt + lm] = C[m][nt][r];
    }
}

// ---------------------------------------------------------------------------
extern "C" void kernel_launch(void* const* d_in, const int* in_sizes, int n_in,
                              void* d_out, int out_size, void* d_ws, size_t ws_size,
                              hipStream_t stream) {
    // inputs: h_v, h_w, edge_features, W1, b1, W2, b2 (fp32; h_v unused)
    const float* h_w = (const float*)d_in[1];
    const float* ef  = (const float*)d_in[2];
    const float* W1  = (const float*)d_in[3];
    const float* b1  = (const float*)d_in[4];
    const float* W2  = (const float*)d_in[5];
    const float* b2  = (const float*)d_in[6];
    float* out = (float*)d_out;

    char* ws = (char*)d_ws;
    uint4*          bpf = (uint4*)ws;                         // 4,456,448 B
    unsigned short* hwb = (unsigned short*)(ws + 4456448);    // 5,120,000 B
    // total ws use: 9,576,448 B

    hipLaunchKernelGGL(prep_all, dim3(NBA + NBC), dim3(256), 0, stream,
                       W2, b2, h_w, bpf, hwb);
    hipLaunchKernelGGL(edge_main, dim3(1000), dim3(256), 0, stream,
                       bpf, (const uint4*)hwb, ef, W1, b1, out);
}